// Round 13
// baseline (15455.348 us; speedup 1.0000x reference)
//
#include <hip/hip_runtime.h>
#include <hip/hip_fp16.h>
#include <cmath>

#define Tn 4096
#define Hn 1024
#define NHn 16
#define HDn 64
#define In 4096
#define Vn 1024
#define NSTEPSn 8

enum { EPI_NONE = 0, EPI_ADD = 1, EPI_SILU = 2, EPI_MUL = 3, EPI_BIAS = 4 };

typedef __attribute__((ext_vector_type(8))) _Float16 f16x8;
typedef __attribute__((ext_vector_type(4))) float f32x4;

// fp32 -> f16 high/low split (RNE), with the LOW plane pre-scaled by 2^11 so
// it stays in f16 NORMAL range. Reconstruction: x ~= h + l * 2^-11, residual
// ~2^-22 relative. The 2^-11 is applied in the GEMM promote (accl accumulator).
__device__ inline unsigned short f16rne(float x) {
    return __half_as_ushort(__float2half(x));
}
__device__ inline float f16tof(unsigned short h) {
    return __half2float(__ushort_as_half(h));
}
__device__ inline void split2(float x, unsigned short& h, unsigned short& l) {
    h = f16rne(x);
    float r = (x - f16tof(h)) * 2048.0f;
    l = f16rne(r);
}

// Async global->LDS, 16B per lane (wave-uniform LDS base; HW scatters lane*16).
__device__ __forceinline__ void gload_lds(const unsigned short* g,
                                          const unsigned short* l) {
    __builtin_amdgcn_global_load_lds(
        (const __attribute__((address_space(1))) unsigned int*)(uintptr_t)g,
        (__attribute__((address_space(3))) unsigned int*)(unsigned int)(uintptr_t)l,
        16, 0, 0);
}

// ---------------- RoPE cos/sin table ----------------
__global__ void rope_tab_kernel(double2* __restrict__ tab) {
    int tid = threadIdx.x;  // 256 threads
    int j = tid >> 5, i = tid & 31;
    double inv = exp(-((double)(2 * i) * (1.0 / (double)HDn)) * 9.210340371976184);
    double ang = (double)j * inv;
    double2 cs;
    cs.x = cos(ang);
    cs.y = sin(ang);
    tab[tid] = cs;
}

// ---------------- Weight pre-split: W[K][N] fp32 -> W2[2][N][K] f16 ----------------
__global__ __launch_bounds__(256) void presplit_kernel(const float* __restrict__ W,
                                                       unsigned short* __restrict__ W2,
                                                       int K, int N) {
    __shared__ float S[64][65];
    int k0 = blockIdx.y * 64, n0 = blockIdx.x * 64;
    int tid = threadIdx.x;
#pragma unroll
    for (int r = 0; r < 4; r++) {
        int idx = tid + r * 256;
        int kr = idx >> 4, c4 = (idx & 15) << 2;
        float4 v = *(const float4*)(W + (size_t)(k0 + kr) * N + n0 + c4);
        S[kr][c4] = v.x;
        S[kr][c4 + 1] = v.y;
        S[kr][c4 + 2] = v.z;
        S[kr][c4 + 3] = v.w;
    }
    __syncthreads();
    size_t PS = (size_t)N * K;
#pragma unroll
    for (int r = 0; r < 4; r++) {
        int idx = tid + r * 256;
        int kq = idx & 15, n = idx >> 4;
        ushort4 hq, lq;
        split2(S[4 * kq + 0][n], hq.x, lq.x);
        split2(S[4 * kq + 1][n], hq.y, lq.y);
        split2(S[4 * kq + 2][n], hq.z, lq.z);
        split2(S[4 * kq + 3][n], hq.w, lq.w);
        size_t off = (size_t)(n0 + n) * K + k0 + 4 * kq;
        *(ushort4*)(W2 + off) = hq;
        *(ushort4*)(W2 + PS + off) = lq;
    }
}

// ---------------- RMSNorm -> f16 h/l planes (f64 math) ----------------
__global__ __launch_bounds__(256) void rmsnorm2_kernel(const float* __restrict__ x,
                                                       const float* __restrict__ w,
                                                       unsigned short* __restrict__ y2,
                                                       size_t stride) {
    int t = blockIdx.x;
    const float4* xr = (const float4*)(x + (size_t)t * Hn);
    float4 v = xr[threadIdx.x];
    double ss = (double)v.x * v.x + (double)v.y * v.y + (double)v.z * v.z + (double)v.w * v.w;
#pragma unroll
    for (int o = 1; o < 64; o <<= 1) ss += __shfl_xor(ss, o, 64);
    __shared__ double red[4];
    if ((threadIdx.x & 63) == 0) red[threadIdx.x >> 6] = ss;
    __syncthreads();
    double tot = red[0] + red[1] + red[2] + red[3];
    double rs = 1.0 / sqrt(tot * (1.0 / Hn) + 1e-6);
    const float4* wr = (const float4*)w;
    float4 wv = wr[threadIdx.x];
    float o[4];
    o[0] = (float)((double)v.x * rs * (double)wv.x);
    o[1] = (float)((double)v.y * rs * (double)wv.y);
    o[2] = (float)((double)v.z * rs * (double)wv.z);
    o[3] = (float)((double)v.w * rs * (double)wv.w);
    ushort4 hq, lq;
    split2(o[0], hq.x, lq.x);
    split2(o[1], hq.y, lq.y);
    split2(o[2], hq.z, lq.z);
    split2(o[3], hq.w, lq.w);
    size_t off = (size_t)t * Hn + threadIdx.x * 4;
    *(ushort4*)(y2 + off) = hq;
    *(ushort4*)(y2 + stride + off) = lq;
}

// ---------------- Attention: 8 (t,head) pairs per wave, stride-8 cols ----------
__global__ __launch_bounds__(256) void attn_kernel(const float* __restrict__ q,
                                                   const float* __restrict__ K0,
                                                   const float* __restrict__ V0,
                                                   const float* __restrict__ EK,
                                                   const float* __restrict__ EV,
                                                   const int* __restrict__ toks,
                                                   const double2* __restrict__ tab,
                                                   unsigned short* __restrict__ ctx2,
                                                   size_t stride, int p) {
    int wv = blockIdx.x * 4 + (threadIdx.x >> 6);  // wave id; 8 pairs per wave
    int lane = threadIdx.x & 63;
    int g = lane >> 3, s = lane & 7;
    int pair = wv * 8 + g;  // t*NH + head
    int t = pair >> 4;
    int head = pair & 15;
    int colbase = pair << 6;  // base into [T*NH*64] arrays

    // ---- q load + rope at position p (partner in-lane: k <-> k+4) ----
    double qv[8], qr[8];
#pragma unroll
    for (int k = 0; k < 8; k++) qv[k] = (double)q[colbase + s + 8 * k];
#pragma unroll
    for (int k = 0; k < 4; k++) {
        double2 cs = tab[p * 32 + s + 8 * k];
        qr[k] = qv[k] * cs.x - qv[k + 4] * cs.y;       // half=0: qv*c - part*s
        qr[k + 4] = qv[k + 4] * cs.x + qv[k] * cs.y;   // half=1: qv*c + part*s
    }

    // ---- scores ----
    double sc[NSTEPSn];
    int tk[NSTEPSn];
    double m = -1e300;
    for (int j = 0; j <= p; j++) {
        double kr[8];
        if (j == 0) {
            tk[0] = 0;
#pragma unroll
            for (int k = 0; k < 8; k++) kr[k] = (double)K0[colbase + s + 8 * k];
        } else {
            int tok = toks[(size_t)t * NSTEPSn + (j - 1)];
            tk[j] = tok;
            size_t eb = (size_t)tok * Hn + (head << 6);
            double kv[8];
#pragma unroll
            for (int k = 0; k < 8; k++) kv[k] = (double)EK[eb + s + 8 * k];
#pragma unroll
            for (int k = 0; k < 4; k++) {
                double2 cs = tab[j * 32 + s + 8 * k];
                kr[k] = kv[k] * cs.x - kv[k + 4] * cs.y;
                kr[k + 4] = kv[k + 4] * cs.x + kv[k] * cs.y;
            }
        }
        double pr = 0.0;
#pragma unroll
        for (int k = 0; k < 8; k++) pr += qr[k] * kr[k];
#pragma unroll
        for (int o = 1; o < 8; o <<= 1) pr += __shfl_xor(pr, o, 64);
        sc[j] = pr * 0.125;
        m = fmax(m, sc[j]);
    }

    // ---- softmax (f32 exp, f64 sum) ----
    double den = 0.0;
    for (int j = 0; j <= p; j++) {
        sc[j] = (double)expf((float)(sc[j] - m));
        den += sc[j];
    }
    double invd = 1.0 / den;

    // ---- PV ----
    double acc[8];
#pragma unroll
    for (int k = 0; k < 8; k++) acc[k] = 0.0;
    for (int j = 0; j <= p; j++) {
        if (j == 0) {
#pragma unroll
            for (int k = 0; k < 8; k++)
                acc[k] += sc[0] * (double)V0[colbase + s + 8 * k];
        } else {
            size_t eb = (size_t)tk[j] * Hn + (head << 6);
#pragma unroll
            for (int k = 0; k < 8; k++)
                acc[k] += sc[j] * (double)EV[eb + s + 8 * k];
        }
    }

#pragma unroll
    for (int k = 0; k < 8; k++) {
        unsigned short h, l;
        split2((float)(acc[k] * invd), h, l);
        ctx2[colbase + s + 8 * k] = h;
        ctx2[stride + colbase + s + 8 * k] = l;
    }
}

// ---------------- f16x2 MFMA GEMM: 64x128 tile, 8 waves, 2-buffer pipeline ----
// C(M x N) = A(M x K) @ B(K x N). A planes [2][M][K] f16, B planes [2][N][K];
// low planes pre-scaled by 2^11. 3 products per K-chunk:
//   Ah*Bh -> acc (unit scale), Ah*Bl' + Al'*Bh -> accl (2^11 scale).
// Promote: accd += acc + accl * 2^-11 (f64) every 4 chunks (f32 accumulates
// K=128 between folds — sqrt(2)x the noise of the twice-validated K=64
// cadence, still far below the f32 reference's own accumulation noise).
// TWO LDS buffers (48KB) -> THREE blocks per CU (144KB LDS, 6 waves/SIMD):
// R11 counters (MfmaUtil 22, VALU 41, HBM 13, Occ 36) showed ~25us of
// barrier/latency stall above the ~20us resource floor; +50% TLP covers it.
// Per chunk: stage(c+1) -> vmcnt(3) [proves chunk c landed: its 3 loads are
// the oldest] -> barrier [makes it block-wide] -> reads -> MFMA -> barrier
// [guards buffer reuse: stage(c+2) at iter c+1 overwrites the buffer read
// here]. Counted vmcnt in steady state; single vmcnt(0) at the last chunk.
// Bank-conflict-free LDS cells: slot = global_slot ^ ((row>>1)&3) -> 2
// lanes/bank on ds_read_b128 (verified: conflicts 4.2M -> 0 in R11).
#define BUFU 12288  // ushorts per buffer: 24KB (A 8KB + B 16KB)
template <int EPI, bool PAIR>
__global__ __launch_bounds__(512, 6) void gemm2_kernel(
    const unsigned short* __restrict__ A2, size_t strideA,
    const unsigned short* __restrict__ B2, size_t strideB, int ldbk,
    float* Cf, unsigned short* C2, size_t strideC,
    const float* aux, int K, int ldc) {
    __shared__ __align__(16) unsigned short lds[2 * BUFU];  // 48 KB

    int tid = threadIdx.x;
    int wv = tid >> 6, lane = tid & 63;
    int wr = wv >> 2;  // 2 m-groups of 32
    int wc = wv & 3;   // 4 n-groups of 32

    // ---- XCD swizzle: GN = 8 fixed (N=1024/128) ----
    int f = blockIdx.x;
    int xcd = f & 7;
    int j = f >> 3;
    int bmPer = gridDim.x >> 6;  // m-blocks per xcd (512->8, 128->2)
    int mblk = (xcd * bmPer + (j >> 3)) * 64;
    int nblk = (j & 7) * 128;

    // ---- staging segments: 24 x 1KB, each wave owns 3 ----
    // row-major cells, slot swizzled by (row>>1)&3; lanes 4q..4q+3 cover one
    // 64B row-slice (permuted) -> coalesced global_load_lds source.
    int rsel = lane >> 2;
    int csel = ((lane & 3) ^ ((lane >> 3) & 3)) << 3;
    const unsigned short* gseg[3];
    unsigned lseg[3];
#pragma unroll
    for (int i = 0; i < 3; i++) {
        int s = wv * 3 + i;
        if (s < 8) {
            int pl = s >> 2, sub = s & 3;
            gseg[i] = A2 + (size_t)pl * strideA +
                      (size_t)(mblk + sub * 16 + rsel) * K + csel;
            lseg[i] = pl * 2048 + sub * 512;
        } else {
            int u = s - 8;
            int pl = u >> 3, sub = u & 7;
            gseg[i] = B2 + (size_t)pl * strideB +
                      (size_t)(nblk + sub * 16 + rsel) * ldbk + csel;
            lseg[i] = 4096 + pl * 4096 + sub * 512;
        }
    }

    f32x4 acc[2][2], accl[2][2];
    double accd[2][2][4];
#pragma unroll
    for (int mt = 0; mt < 2; mt++)
#pragma unroll
        for (int nt = 0; nt < 2; nt++) {
            acc[mt][nt] = (f32x4){0.f, 0.f, 0.f, 0.f};
            accl[mt][nt] = (f32x4){0.f, 0.f, 0.f, 0.f};
#pragma unroll
            for (int r = 0; r < 4; r++) accd[mt][nt][r] = 0.0;
        }

    int rA = lane & 15;
    // fragment offset within a 512-ushort segment: row rA, slot hi^((rA>>1)&3)
    unsigned fo = (rA << 5) + ((((lane >> 4) ^ ((lane >> 1) & 3))) << 3);

    int nc = K >> 5;  // 32-K chunks

    // ---- prologue: stage chunk 0 -> buf0 ----
#pragma unroll
    for (int i = 0; i < 3; i++) gload_lds(gseg[i], lds + lseg[i]);

    for (int c = 0; c < nc; ++c) {
        const unsigned short* Ar = lds + (c & 1) * BUFU;
        const bool nx = (c + 1 < nc);

        // stage chunk c+1 into the other buffer (its previous contents,
        // chunk c-1, were consumed before iter c-1's end barrier)
        if (nx) {
            int koff = (c + 1) << 5;
            unsigned short* Lw = lds + ((c + 1) & 1) * BUFU;
            gload_lds(gseg[0] + koff, Lw + lseg[0]);
            gload_lds(gseg[1] + koff, Lw + lseg[1]);
            gload_lds(gseg[2] + koff, Lw + lseg[2]);
            asm volatile("s_waitcnt vmcnt(3)" ::: "memory");  // chunk c landed
        } else {
            asm volatile("s_waitcnt vmcnt(0)" ::: "memory");  // tail drain
        }
        __builtin_amdgcn_s_barrier();  // chunk c visible block-wide

        // all 8 fragment reads for chunk c
        f16x8 Ah[2], Al[2], Bh[2], Bl[2];
#pragma unroll
        for (int mt = 0; mt < 2; mt++) {
            Ah[mt] = *(const f16x8*)(Ar + (wr * 2 + mt) * 512 + fo);
            Al[mt] = *(const f16x8*)(Ar + 2048 + (wr * 2 + mt) * 512 + fo);
        }
#pragma unroll
        for (int nt = 0; nt < 2; nt++) {
            Bh[nt] = *(const f16x8*)(Ar + 4096 + (wc * 2 + nt) * 512 + fo);
            Bl[nt] = *(const f16x8*)(Ar + 8192 + (wc * 2 + nt) * 512 + fo);
        }

        // promote completed chunks (every 4 chunks; overlaps ds latency)
        if (c > 0 && (c & 3) == 0) {
#pragma unroll
            for (int mt = 0; mt < 2; mt++)
#pragma unroll
                for (int nt = 0; nt < 2; nt++)
#pragma unroll
                    for (int r = 0; r < 4; r++) {
                        accd[mt][nt][r] += (double)acc[mt][nt][r] +
                                           (double)accl[mt][nt][r] * 4.8828125e-4;
                        acc[mt][nt][r] = 0.f;
                        accl[mt][nt][r] = 0.f;
                    }
        }

        __builtin_amdgcn_s_setprio(1);
#pragma unroll
        for (int mt = 0; mt < 2; mt++)
#pragma unroll
            for (int nt = 0; nt < 2; nt++)
                acc[mt][nt] = __builtin_amdgcn_mfma_f32_16x16x32_f16(
                    Ah[mt], Bh[nt], acc[mt][nt], 0, 0, 0);
#pragma unroll
        for (int mt = 0; mt < 2; mt++)
#pragma unroll
            for (int nt = 0; nt < 2; nt++)
                accl[mt][nt] = __builtin_amdgcn_mfma_f32_16x16x32_f16(
                    Ah[mt], Bl[nt], accl[mt][nt], 0, 0, 0);
#pragma unroll
        for (int mt = 0; mt < 2; mt++)
#pragma unroll
            for (int nt = 0; nt < 2; nt++)
                accl[mt][nt] = __builtin_amdgcn_mfma_f32_16x16x32_f16(
                    Al[mt], Bh[nt], accl[mt][nt], 0, 0, 0);
        __builtin_amdgcn_s_setprio(0);

        __builtin_amdgcn_s_barrier();  // all waves done reading buf[c&1]
    }

    // final promote (last 4 chunks)
#pragma unroll
    for (int mt = 0; mt < 2; mt++)
#pragma unroll
        for (int nt = 0; nt < 2; nt++)
#pragma unroll
            for (int r = 0; r < 4; r++)
                accd[mt][nt][r] += (double)acc[mt][nt][r] +
                                   (double)accl[mt][nt][r] * 4.8828125e-4;

    // ---- epilogue (f64), write f32 or f16 h/l pair ----
#pragma unroll
    for (int mt = 0; mt < 2; mt++)
#pragma unroll
        for (int nt = 0; nt < 2; nt++) {
            int n = nblk + wc * 32 + nt * 16 + (lane & 15);
            int mb = mblk + wr * 32 + mt * 16 + ((lane >> 4) << 2);
#pragma unroll
            for (int r = 0; r < 4; r++) {
                int m = mb + r;
                size_t off = (size_t)m * ldc + n;
                double v = accd[mt][nt][r];
                if (EPI == EPI_ADD) v += (double)aux[off];
                if (EPI == EPI_SILU) {
                    float vf = (float)v;
                    v = (double)(vf / (1.0f + expf(-vf)));
                }
                if (EPI == EPI_MUL) v *= (double)aux[off];
                if (EPI == EPI_BIAS) v += (double)aux[n];
                if (PAIR) {
                    unsigned short h, l;
                    split2((float)v, h, l);
                    C2[off] = h;
                    C2[strideC + off] = l;
                } else {
                    Cf[off] = (float)v;
                }
            }
        }
}

// ---------------- Argmax over f32 logits (first-max tie-break) ----------------
__global__ __launch_bounds__(256) void argmax_kernel(const float* __restrict__ logits,
                                                     int* __restrict__ out_tok, int p) {
    int t = blockIdx.x;
    const float* lr = logits + (size_t)t * Vn;
    float bv = -INFINITY;
    int bi = 0x7fffffff;
    for (int j = threadIdx.x; j < Vn; j += 256) {
        float v = lr[j];
        if (v > bv || (v == bv && j < bi)) {
            bv = v;
            bi = j;
        }
    }
#pragma unroll
    for (int o = 1; o < 64; o <<= 1) {
        float ov = __shfl_xor(bv, o, 64);
        int oi = __shfl_xor(bi, o, 64);
        if (ov > bv || (ov == bv && oi < bi)) {
            bv = ov;
            bi = oi;
        }
    }
    __shared__ float sv[4];
    __shared__ int si[4];
    if ((threadIdx.x & 63) == 0) {
        sv[threadIdx.x >> 6] = bv;
        si[threadIdx.x >> 6] = bi;
    }
    __syncthreads();
    if (threadIdx.x == 0) {
        for (int w = 1; w < 4; w++) {
            if (sv[w] > bv || (sv[w] == bv && si[w] < bi)) {
                bv = sv[w];
                bi = si[w];
            }
        }
        out_tok[(size_t)t * NSTEPSn + p] = bi;
    }
}

// ---------------- Embedding gather ----------------
__global__ __launch_bounds__(256) void embed_kernel(const float* __restrict__ E,
                                                    const int* __restrict__ toks,
                                                    float* __restrict__ x, int p) {
    int t = blockIdx.x;
    int tok = toks[(size_t)t * NSTEPSn + p];
    float4 v = ((const float4*)(E + (size_t)tok * Hn))[threadIdx.x];
    ((float4*)(x + (size_t)t * Hn))[threadIdx.x] = v;
}

extern "C" void kernel_launch(void* const* d_in, const int* in_sizes, int n_in,
                              void* d_out, int out_size, void* d_ws, size_t ws_size,
                              hipStream_t stream) {
    const float* x0 = (const float*)d_in[0];
    const float* Wq = (const float*)d_in[1];
    const float* Wk = (const float*)d_in[2];
    const float* Wv = (const float*)d_in[3];
    const float* Wo = (const float*)d_in[4];
    const float* Wg = (const float*)d_in[5];
    const float* Wu = (const float*)d_in[6];
    const float* Wd = (const float*)d_in[7];
    const float* n1 = (const float*)d_in[8];
    const float* n2 = (const float*)d_in[9];
    const float* Emb = (const float*)d_in[10];
    const float* Wout = (const float*)d_in[11];
    const float* bout = (const float*)d_in[12];
    int* toks = (int*)d_out;

    float* ws = (float*)d_ws;
    const size_t M1 = 1024 * 1024;
    float* EK = ws;                  // V x H fp32           4MB
    float* EV = ws + 1 * M1;         //                      4MB
    float* K0 = ws + 2 * M1;         // T x H fp32           16MB
    float* V0 = ws + 6 * M1;         //                      16MB
    float* xb = ws + 10 * M1;        // residual hidden      16MB
    float* qb = ws + 14 * M1;        // q / MLP acc / logits 16MB
    float* Gc = ws + 18 * M1;        // silu chunk fp32      16MB
    unsigned short* s2a = (unsigned short*)(ws + 22 * M1);  // h/l TxH  (16MB used)
    unsigned short* s2g = (unsigned short*)(ws + 28 * M1);  // h/l TxH  (16MB used)
    double2* tab = (double2*)(ws + 34 * M1);                // 256 double2  4KB
    unsigned short* W2q = (unsigned short*)(ws + 34 * M1 + 1024);  // 2 planes used
    unsigned short* W2k = W2q + 3 * M1;
    unsigned short* W2v = W2k + 3 * M1;
    unsigned short* W2o = W2v + 3 * M1;
    unsigned short* W2t = W2o + 3 * M1;  // Wout
    unsigned short* W2g = W2t + 3 * M1;
    unsigned short* W2u = W2g + 12 * M1;
    unsigned short* W2d = W2u + 12 * M1;
    // total ~= 238 MB (offsets kept from the bf16x3 layout; 3rd planes unused)

    const size_t STH = (size_t)Tn * Hn;  // plane stride, T x 1024
    const size_t SVH = (size_t)Vn * Hn;  // plane stride, V x H
    const size_t SW1 = M1;               // plane stride, 1M-element weights
    const size_t SW4 = 4 * M1;           // plane stride, 4M-element weights

    dim3 blk(256);
    dim3 gblk(512);
    const int gTH = 512;  // (M/64=64) x (N/128=8), 1D swizzled -> 3 blocks/CU
    const int gVH = 128;  // (M/64=16) x 8
    const int gAT = (Tn * NHn) / 32;  // attn: 8 pairs/wave x 4 waves = 2048

    // ---- One-time precompute ----
    rope_tab_kernel<<<1, 256, 0, stream>>>(tab);
    presplit_kernel<<<dim3(16, 16), blk, 0, stream>>>(Wq, W2q, Hn, Hn);
    presplit_kernel<<<dim3(16, 16), blk, 0, stream>>>(Wk, W2k, Hn, Hn);
    presplit_kernel<<<dim3(16, 16), blk, 0, stream>>>(Wv, W2v, Hn, Hn);
    presplit_kernel<<<dim3(16, 16), blk, 0, stream>>>(Wo, W2o, Hn, Hn);
    presplit_kernel<<<dim3(16, 16), blk, 0, stream>>>(Wout, W2t, Hn, Vn);
    presplit_kernel<<<dim3(In / 64, Hn / 64), blk, 0, stream>>>(Wg, W2g, Hn, In);
    presplit_kernel<<<dim3(In / 64, Hn / 64), blk, 0, stream>>>(Wu, W2u, Hn, In);
    presplit_kernel<<<dim3(Hn / 64, In / 64), blk, 0, stream>>>(Wd, W2d, In, Hn);
    rmsnorm2_kernel<<<Vn, 256, 0, stream>>>(Emb, n1, s2a, SVH);
    gemm2_kernel<EPI_NONE, false><<<gVH, gblk, 0, stream>>>(
        s2a, SVH, W2k, SW1, Hn, EK, nullptr, 0, nullptr, Hn, Hn);
    gemm2_kernel<EPI_NONE, false><<<gVH, gblk, 0, stream>>>(
        s2a, SVH, W2v, SW1, Hn, EV, nullptr, 0, nullptr, Hn, Hn);

    for (int p = 0; p < NSTEPSn; p++) {
        const float* src = (p == 0) ? x0 : xb;

        rmsnorm2_kernel<<<Tn, 256, 0, stream>>>(src, n1, s2a, STH);
        gemm2_kernel<EPI_NONE, false><<<gTH, gblk, 0, stream>>>(
            s2a, STH, W2q, SW1, Hn, qb, nullptr, 0, nullptr, Hn, Hn);
        if (p == 0) {
            gemm2_kernel<EPI_NONE, false><<<gTH, gblk, 0, stream>>>(
                s2a, STH, W2k, SW1, Hn, K0, nullptr, 0, nullptr, Hn, Hn);
            gemm2_kernel<EPI_NONE, false><<<gTH, gblk, 0, stream>>>(
                s2a, STH, W2v, SW1, Hn, V0, nullptr, 0, nullptr, Hn, Hn);
        }
        attn_kernel<<<gAT, 256, 0, stream>>>(qb, K0, V0, EK, EV, toks,
                                             tab, s2a, STH, p);
        // h2 = ctx @ Wo + src  (in-place into xb when src == xb)
        gemm2_kernel<EPI_ADD, false><<<gTH, gblk, 0, stream>>>(
            s2a, STH, W2o, SW1, Hn, xb, nullptr, 0, src, Hn, Hn);
        rmsnorm2_kernel<<<Tn, 256, 0, stream>>>(xb, n2, s2a, STH);
        // Gated MLP, chunked over I (4 x 1024): G (silu -> Gc f32), U (mul by
        // Gc -> s2g h/l), then chunk-accumulated @Wd into qb.
        for (int c = 0; c < 4; c++) {
            gemm2_kernel<EPI_SILU, false><<<gTH, gblk, 0, stream>>>(
                s2a, STH, W2g + (size_t)c * M1, SW4, Hn,
                Gc, nullptr, 0, nullptr, Hn, 1024);
            gemm2_kernel<EPI_MUL, true><<<gTH, gblk, 0, stream>>>(
                s2a, STH, W2u + (size_t)c * M1, SW4, Hn,
                nullptr, s2g, STH, Gc, Hn, 1024);
            if (c < 3) {
                gemm2_kernel<EPI_ADD, false><<<gTH, gblk, 0, stream>>>(
                    s2g, STH, W2d + (size_t)c * 1024, SW4, In,
                    qb, nullptr, 0, (c == 0) ? xb : qb, Hn, Hn);
            } else {
                gemm2_kernel<EPI_ADD, true><<<gTH, gblk, 0, stream>>>(
                    s2g, STH, W2d + (size_t)c * 1024, SW4, In,
                    nullptr, s2a, STH, qb, Hn, Hn);
            }
        }
        // logits = out @ Wout + bout  (into qb)
        gemm2_kernel<EPI_BIAS, false><<<gTH, gblk, 0, stream>>>(
            s2a, STH, W2t, SW1, Hn, qb, nullptr, 0, bout, Hn, Vn);
        argmax_kernel<<<Tn, 256, 0, stream>>>(qb, toks, p);
        if (p < NSTEPSn - 1) embed_kernel<<<Tn, 256, 0, stream>>>(Emb, toks, xb, p);
    }
}